// Round 12
// baseline (348.463 us; speedup 1.0000x reference)
//
#include <hip/hip_runtime.h>
#include <math.h>

#define NN 100000
#define NE 1600000
#define PERIODS 12
#define SLOTS 48     /* fixed Poisson(16) graph: max degree well below 48 (verified passing) */
#define NBUCK 98     /* ceil(NN/1024) node buckets */
#define FRAG 256     /* pass-1 partition blocks */
#define CAPB 128     /* per (bucket,block) cell capacity: mean 63.8, +8 sigma */

typedef unsigned short ushort_t;
typedef __attribute__((ext_vector_type(8))) short short8;
typedef __attribute__((ext_vector_type(16))) float floatx16;

union F4S8 { float4 f; short8 s; int4 i; };

__device__ __forceinline__ ushort_t f2bf(float f) {  // RNE fp32->bf16
  unsigned u = __float_as_uint(f);
  unsigned r = u + 0x7fffu + ((u >> 16) & 1u);
  return (ushort_t)(r >> 16);
}

__device__ __forceinline__ float bflo(unsigned u) { return __uint_as_float(u << 16); }
__device__ __forceinline__ float bfhi(unsigned u) { return __uint_as_float(u & 0xffff0000u); }

// A-tile offset for y element e (= f*12+p) of node slot 0: row p, col f;
// row stride 32 B (32 rows x 16 cols bf16). Node slot 1: +384 bytes.
__device__ __forceinline__ unsigned aoff2(unsigned e) {
  unsigned f = (e * 43691u) >> 19;   // e/12 for e<192
  unsigned p = e - f * 12u;
  return p * 32u + f * 2u;
}

// ---------------- pass 1: radix partition (LDS atomics only) + fused prep ----
// R9 confirmed: eliminating device-scope per-edge atomics was the build win.
__global__ __launch_bounds__(256) void k_part(
    const int* __restrict__ src, const int* __restrict__ dst,
    int* __restrict__ cnt_blk, int* __restrict__ part,
    const float* __restrict__ attn,
    const float* __restrict__ czw, const float* __restrict__ czb,
    const float* __restrict__ chw, const float* __restrict__ chb,
    const float* __restrict__ lzw, const float* __restrict__ lzb,
    const float* __restrict__ lhw, const float* __restrict__ lhb,
    ushort_t* __restrict__ Bz32, ushort_t* __restrict__ Bh32,
    float2* __restrict__ cb2, float* __restrict__ probs_ext) {
  if (blockIdx.x == FRAG) {
    // ---- prep: fused weights in 32x32x16 B-frag order + softmax(attn) ----
    // H0 stays zero all periods => R path dead; only top 64 rows of lin_*.
    for (int t5 = threadIdx.x; t5 < 1024; t5 += 256) {
      int f = t5 >> 6, c = t5 & 63;
      float az = 0.f, ah = 0.f;
#pragma unroll 8
      for (int k = 0; k < 64; ++k) {
        az += czw[f * 64 + k] * lzw[k * 64 + c];
        ah += chw[f * 64 + k] * lhw[k * 64 + c];
      }
      int idx = (((c >> 5) * 64) + ((f >> 3) * 32) + (c & 31)) * 8 + (f & 7);
      Bz32[idx] = f2bf(az);
      Bh32[idx] = f2bf(ah);
    }
    if (threadIdx.x < 64) {
      int t = threadIdx.x;
      float vz = lzb[t], vh = lhb[t];
      for (int k = 0; k < 64; ++k) {
        vz += czb[k] * lzw[k * 64 + t];
        vh += chb[k] * lhw[k * 64 + t];
      }
      cb2[t] = make_float2(vz, vh);
    }
    if (threadIdx.x == 0) {
      float m = -1e30f;
      for (int p = 0; p < PERIODS; ++p) m = fmaxf(m, attn[p]);
      float e[PERIODS], s = 0.f;
      for (int p = 0; p < PERIODS; ++p) { e[p] = __expf(attn[p] - m); s += e[p]; }
      float inv = 1.f / s;
      for (int r = 0; r < 32; ++r)
        probs_ext[r] = (r < 12) ? e[r] * inv : ((r < 24) ? e[r - 12] * inv : 0.f);
    }
    return;
  }
  __shared__ int cnt[NBUCK];
  int tid = threadIdx.x, blk = blockIdx.x;
  for (int c = tid; c < NBUCK; c += 256) cnt[c] = 0;
  __syncthreads();
  for (unsigned i = blk * 256u + tid; i < NE / 4; i += FRAG * 256u) {
    int4 dv = ((const int4*)dst)[i];
    int4 sv = ((const int4*)src)[i];
    int d[4] = {dv.x, dv.y, dv.z, dv.w};
    int s[4] = {sv.x, sv.y, sv.z, sv.w};
#pragma unroll
    for (int k = 0; k < 4; ++k) {
      int cls = d[k] >> 10;
      int slot = atomicAdd(&cnt[cls], 1);
      if (slot < CAPB)
        part[(size_t)(cls * FRAG + blk) * CAPB + slot] = (d[k] & 1023) | (s[k] << 10);
    }
  }
  __syncthreads();
  for (int c = tid; c < NBUCK; c += 256) cnt_blk[blk * NBUCK + c] = cnt[c];
}

// ---------------- pass 2: per-bucket CSR build + FUSED prescale ----------
// R11 insight: deg for this bucket is already in LDS after the histogram;
// fuse the bf16 prescale here (block owns a contiguous 1024-node x/xs slab,
// fully coalesced) -> one fewer launch, no global deg round-trip. Bucket 97
// also zero-fills the 4 dummy pad rows used by k_main's branch-free tails.
__global__ __launch_bounds__(1024) void k_csr(const int* __restrict__ cnt_blk,
                                              const int* __restrict__ part,
                                              int* __restrict__ deg,
                                              int* __restrict__ csr,
                                              const float* __restrict__ x,
                                              ushort_t* __restrict__ xs) {
  __shared__ int fcnt[FRAG];
  __shared__ int cnt[1024];
  int b = blockIdx.x, tid = threadIdx.x;
  if (tid < FRAG) {
    int c = cnt_blk[tid * NBUCK + b];
    fcnt[tid] = c < CAPB ? c : CAPB;
  }
  cnt[tid] = 0;
  __syncthreads();
  int g = tid >> 6, it = tid & 63;   // 16 concurrent fragment columns
  for (int f = g; f < FRAG; f += 16) {
    int c = fcnt[f];
    const int* frag = part + (size_t)(b * FRAG + f) * CAPB;
    for (int i2 = it; i2 < c; i2 += 64) {
      int r = frag[i2];
      int dl = r & 1023;
      int slot = atomicAdd(&cnt[dl], 1);
      if (slot < SLOTS) csr[((size_t)(b * 1024 + dl)) * SLOTS + slot] = r >> 10;
    }
  }
  __syncthreads();
  int node = b * 1024 + tid;
  if (node < NN) deg[node] = cnt[tid];

  // ---- fused prescale: wave w handles nodes w*64..w*64+63 of this bucket
  int w = g, l = it;
  char* ob = (char*)xs;
  const char* xb = (const char*)x;
#pragma unroll 1
  for (int j = 0; j < 64; ++j) {
    int n = b * 1024 + w * 64 + j;
    if (n >= NN + 4) break;            // wave-uniform
    unsigned ro = (unsigned)n * 384u;
    if (n >= NN) {                     // dummy pad rows NN..NN+3: zeros
      *(unsigned*)(ob + ro + (unsigned)l * 4u) = 0u;
      *(ushort_t*)(ob + ro + 256u + (unsigned)l * 2u) = 0;
      continue;
    }
    float dn = rsqrtf((float)(cnt[w * 64 + j] + 1));   // LDS broadcast read
    unsigned nb = (unsigned)n * 768u;
    float2 p = *(const float2*)(xb + nb + (unsigned)l * 8u);       // elems 2l,2l+1
    float qv = *(const float*)(xb + nb + 512u + (unsigned)l * 4u); // elem 128+l
    unsigned pk = (unsigned)f2bf(dn * p.x) | ((unsigned)f2bf(dn * p.y) << 16);
    *(unsigned*)(ob + ro + (unsigned)l * 4u) = pk;
    *(ushort_t*)(ob + ro + 256u + (unsigned)l * 2u) = f2bf(dn * qv);
  }
}

// ---------------- fused gather + 32x32x16-MFMA collapsed-GRU + head ----------
// TWO nodes per wave (R10 gather structure: min-paired loop + tails — R11's
// branchless max-padded loop measured slower). 4 MFMAs per node pair.
__global__ __launch_bounds__(256) void k_main(
    const ushort_t* __restrict__ xs, const int* __restrict__ csr,
    const int* __restrict__ deg,
    const ushort_t* __restrict__ Bz32, const ushort_t* __restrict__ Bh32,
    const float2* __restrict__ cb2, const float* __restrict__ probs_ext,
    const float* __restrict__ out_w, const float* __restrict__ out_b,
    float* __restrict__ out) {
  __shared__ ushort_t Alds[4][32][16];   // per wave 1KB, row stride 32B
  int wid = __builtin_amdgcn_readfirstlane(threadIdx.x >> 6);
  int l = threadIdx.x & 63;
  int nA = blockIdx.x * 8 + wid * 2;     // grid = 12500 exact
  int nB = nA + 1;
  char* albase = (char*)&Alds[wid][0][0];
  if (l < 16) *(int4*)(albase + 768 + l * 16) = make_int4(0, 0, 0, 0);  // rows 24-31

  const char* xb = (const char*)xs;
  unsigned offA = (unsigned)l * 4u;          // bf16 pair: elems 2l, 2l+1
  unsigned offB = 256u + (unsigned)l * 2u;   // bf16: elem 128+l

  // self terms
  unsigned ba = (unsigned)nA * 384u, bb = (unsigned)nB * 384u;
  unsigned sua = *(const unsigned*)(xb + ba + offA);
  unsigned sqa = *(const ushort_t*)(xb + ba + offB);
  unsigned sub = *(const unsigned*)(xb + bb + offA);
  unsigned sqb = *(const ushort_t*)(xb + bb + offB);
  float aA0 = bflo(sua), aA1 = bfhi(sua), aA2 = bflo(sqa);
  float aB0 = bflo(sub), aB1 = bfhi(sub), aB2 = bflo(sqb);

  int2 dd = *(const int2*)(deg + nA);   // nA even -> 8B aligned
  int dA = dd.x, dB = dd.y;
  int cA = dA < SLOTS ? dA : SLOTS, cB = dB < SLOTS ? dB : SLOTS;
  const int* bktA = csr + (size_t)nA * SLOTS;   // wave-uniform -> s_loads
  const int* bktB = bktA + SLOTS;

  auto batchA = [&](int i) {
    int4 s4 = *(const int4*)(bktA + i);
    unsigned b0 = (unsigned)s4.x * 384u, b1 = (unsigned)s4.y * 384u;
    unsigned b2 = (unsigned)s4.z * 384u, b3 = (unsigned)s4.w * 384u;
    unsigned u0 = *(const unsigned*)(xb + b0 + offA), q0 = *(const ushort_t*)(xb + b0 + offB);
    unsigned u1 = *(const unsigned*)(xb + b1 + offA), q1 = *(const ushort_t*)(xb + b1 + offB);
    unsigned u2 = *(const unsigned*)(xb + b2 + offA), q2 = *(const ushort_t*)(xb + b2 + offB);
    unsigned u3 = *(const unsigned*)(xb + b3 + offA), q3 = *(const ushort_t*)(xb + b3 + offB);
    aA0 += bflo(u0); aA1 += bfhi(u0); aA2 += bflo(q0);
    aA0 += bflo(u1); aA1 += bfhi(u1); aA2 += bflo(q1);
    aA0 += bflo(u2); aA1 += bfhi(u2); aA2 += bflo(q2);
    aA0 += bflo(u3); aA1 += bfhi(u3); aA2 += bflo(q3);
  };
  auto batchB = [&](int i) {
    int4 s4 = *(const int4*)(bktB + i);
    unsigned b0 = (unsigned)s4.x * 384u, b1 = (unsigned)s4.y * 384u;
    unsigned b2 = (unsigned)s4.z * 384u, b3 = (unsigned)s4.w * 384u;
    unsigned u0 = *(const unsigned*)(xb + b0 + offA), q0 = *(const ushort_t*)(xb + b0 + offB);
    unsigned u1 = *(const unsigned*)(xb + b1 + offA), q1 = *(const ushort_t*)(xb + b1 + offB);
    unsigned u2 = *(const unsigned*)(xb + b2 + offA), q2 = *(const ushort_t*)(xb + b2 + offB);
    unsigned u3 = *(const unsigned*)(xb + b3 + offA), q3 = *(const ushort_t*)(xb + b3 + offB);
    aB0 += bflo(u0); aB1 += bfhi(u0); aB2 += bflo(q0);
    aB0 += bflo(u1); aB1 += bfhi(u1); aB2 += bflo(q1);
    aB0 += bflo(u2); aB1 += bfhi(u2); aB2 += bflo(q2);
    aB0 += bflo(u3); aB1 += bfhi(u3); aB2 += bflo(q3);
  };

  int cm = cA < cB ? cA : cB;
  int iA = 0, iB = 0;
  for (; iA + 4 <= cm; iA += 4, iB += 4) { batchA(iA); batchB(iB); }
  for (; iA + 4 <= cA; iA += 4) batchA(iA);
  for (; iB + 4 <= cB; iB += 4) batchB(iB);
  for (; iA < cA; ++iA) {
    int s = bktA[iA];
    unsigned b = (unsigned)s * 384u;
    unsigned u = *(const unsigned*)(xb + b + offA), q = *(const ushort_t*)(xb + b + offB);
    aA0 += bflo(u); aA1 += bfhi(u); aA2 += bflo(q);
  }
  for (; iB < cB; ++iB) {
    int s = bktB[iB];
    unsigned b = (unsigned)s * 384u;
    unsigned u = *(const unsigned*)(xb + b + offA), q = *(const ushort_t*)(xb + b + offB);
    aB0 += bflo(u); aB1 += bfhi(u); aB2 += bflo(q);
  }
  float dnA = rsqrtf((float)(dA + 1)), dnB = rsqrtf((float)(dB + 1));
  float yA0 = dnA * aA0, yA1 = dnA * aA1, yA2 = dnA * aA2;
  float yB0 = dnB * aB0, yB1 = dnB * aB1, yB2 = dnB * aB2;

  // ---- scatter both nodes' y into the 32x16 A-tile; single fence before read
  unsigned o0 = aoff2(2u * l), o1 = aoff2(2u * l + 1u), o2 = aoff2(128u + (unsigned)l);
  *(ushort_t*)(albase + o0) = f2bf(yA0);
  *(ushort_t*)(albase + o1) = f2bf(yA1);
  *(ushort_t*)(albase + o2) = f2bf(yA2);
  *(ushort_t*)(albase + 384u + o0) = f2bf(yB0);
  *(ushort_t*)(albase + 384u + o1) = f2bf(yB1);
  *(ushort_t*)(albase + 384u + o2) = f2bf(yB2);
  asm volatile("s_waitcnt lgkmcnt(0)" ::: "memory");
  F4S8 afr;
  afr.f = *(const float4*)(albase + (unsigned)(l & 31) * 32u + (unsigned)(l >> 5) * 16u);

  // ---- B fragments: 2 tiles x {z,h}, 16B/lane each (no pad lanes, K=16)
  F4S8 bz0, bz1, bh0, bh1;
  bz0.f = ((const float4*)Bz32)[l];
  bz1.f = ((const float4*)Bz32)[64 + l];
  bh0.f = ((const float4*)Bh32)[l];
  bh1.f = ((const float4*)Bh32)[64 + l];

  floatx16 zero16;
#pragma unroll
  for (int r = 0; r < 16; ++r) zero16[r] = 0.f;
  floatx16 az0 = __builtin_amdgcn_mfma_f32_32x32x16_bf16(afr.s, bz0.s, zero16, 0, 0, 0);
  floatx16 az1 = __builtin_amdgcn_mfma_f32_32x32x16_bf16(afr.s, bz1.s, zero16, 0, 0, 0);
  floatx16 ah0 = __builtin_amdgcn_mfma_f32_32x32x16_bf16(afr.s, bh0.s, zero16, 0, 0, 0);
  floatx16 ah1 = __builtin_amdgcn_mfma_f32_32x32x16_bf16(afr.s, bh1.s, zero16, 0, 0, 0);

  // ---- gates. C: col=lane&31(+32t), row=(reg&3)+8*(reg>>2)+4*(lane>>5).
  float2 cbv0 = cb2[l & 31], cbv1 = cb2[(l & 31) + 32];
  float prv[12];
  unsigned sby = (l & 32u) >> 1;   // (lane>>5)*16 bytes
#pragma unroll
  for (int r = 0; r < 12; ++r) {
    const int rb = (r & 3) + 8 * (r >> 2);
    prv[r] = *(const float*)((const char*)probs_ext + rb * 4 + sby);
  }
  bool sh = (l & 32) != 0;
  float hA[2], hB[2];
#pragma unroll
  for (int t = 0; t < 2; ++t) {
    float g0 = 0.f, g1 = 0.f, g2 = 0.f;
    float2 cbv = t ? cbv1 : cbv0;
#pragma unroll
    for (int r = 0; r < 12; ++r) {
      float zz = (t ? az1[r] : az0[r]) + cbv.x;
      float hh = (t ? ah1[r] : ah0[r]) + cbv.y;
      float ez = __expf(zz);
      float e2h = __expf(2.f * hh);
      float val = (e2h - 1.f) * __builtin_amdgcn_rcpf((1.f + ez) * (e2h + 1.f));
      float c = prv[r] * val;
      if ((r >> 2) == 0) g0 += c;
      else if ((r >> 2) == 1) g1 += c;
      else g2 += c;
    }
    float pa = g0 + (sh ? 0.f : g1);
    float pb = g2 + (sh ? g1 : 0.f);
    pa += __shfl_xor(pa, 32, 64);
    pb += __shfl_xor(pb, 32, 64);
    hA[t] = fmaxf(pa, 0.f);
    hB[t] = fmaxf(pb, 0.f);
  }

  // ---- head: half s=0 computes node A, s=1 node B; lane has feats {c0, c0+32}
  int c0 = l & 31;
  float4 w0 = ((const float4*)out_w)[c0];
  float4 w1 = ((const float4*)out_w)[c0 + 32];
  float h0 = sh ? hB[0] : hA[0];
  float h1 = sh ? hB[1] : hA[1];
  float l0 = h0 * w0.x; l0 = fmaf(h1, w1.x, l0);
  float l1 = h0 * w0.y; l1 = fmaf(h1, w1.y, l1);
  float l2 = h0 * w0.z; l2 = fmaf(h1, w1.z, l2);
  float l3 = h0 * w0.w; l3 = fmaf(h1, w1.w, l3);
#pragma unroll
  for (int o = 1; o < 32; o <<= 1) {   // stays within each 32-lane half
    l0 += __shfl_xor(l0, o, 64);
    l1 += __shfl_xor(l1, o, 64);
    l2 += __shfl_xor(l2, o, 64);
    l3 += __shfl_xor(l3, o, 64);
  }
  l0 += out_b[0]; l1 += out_b[1]; l2 += out_b[2]; l3 += out_b[3];
  float m = fmaxf(fmaxf(l0, l1), fmaxf(l2, l3));
  float e0 = __expf(l0 - m), e1 = __expf(l1 - m), e2 = __expf(l2 - m), e3 = __expf(l3 - m);
  float inv = __builtin_amdgcn_rcpf(e0 + e1 + e2 + e3);
  if (c0 < 4) {
    float v = (c0 == 0) ? e0 * inv : (c0 == 1) ? e1 * inv : (c0 == 2) ? e2 * inv : e3 * inv;
    out[(size_t)(sh ? nB : nA) * 4 + c0] = v;
  }
}

extern "C" void kernel_launch(void* const* d_in, const int* in_sizes, int n_in,
                              void* d_out, int out_size, void* d_ws, size_t ws_size,
                              hipStream_t stream) {
  const float* x    = (const float*)d_in[0];
  const int*   ei   = (const int*)d_in[1];   // (2, NE): src row then dst row
  const float* attn = (const float*)d_in[2];
  const float* czw  = (const float*)d_in[3];
  const float* czb  = (const float*)d_in[4];
  // d_in[5..6]: conv_r_* dead (H0*R == 0); d_in[11..12]: lin_r_* dead
  const float* chw  = (const float*)d_in[7];
  const float* chb  = (const float*)d_in[8];
  const float* lzw  = (const float*)d_in[9];
  const float* lzb  = (const float*)d_in[10];
  const float* lhw  = (const float*)d_in[13];
  const float* lhb  = (const float*)d_in[14];
  const float* outw = (const float*)d_in[15];
  const float* outb = (const float*)d_in[16];
  float* out = (float*)d_out;

  char* ws = (char*)d_ws;
  size_t off = 0;
  auto alloc = [&](size_t bytes) {
    void* p = ws + off;
    off += (bytes + 255) & ~(size_t)255;
    return p;
  };
  int*      deg       = (int*)alloc((size_t)NN * 4);                 // 0.4 MB
  int*      csr       = (int*)alloc((size_t)NN * SLOTS * 4);         // 19.2 MB
  // part (12.9 MB) overlaid with xs (38.4 MB + 4 dummy rows): part is fully
  // consumed by k_csr before k_csr's fused prescale writes xs... NOT true in
  // one kernel — so part and xs must NOT alias anymore. Separate regions.
  int*      part      = (int*)alloc((size_t)NBUCK * FRAG * CAPB * 4); // 12.9 MB
  ushort_t* xs        = (ushort_t*)alloc((size_t)(NN + 4) * 192 * 2); // 38.4 MB
  int*      cnt_blk   = (int*)alloc((size_t)FRAG * NBUCK * 4);       // 100 KB
  ushort_t* Bz32      = (ushort_t*)alloc(2 * 64 * 8 * 2);
  ushort_t* Bh32      = (ushort_t*)alloc(2 * 64 * 8 * 2);
  float2*   cb2       = (float2*)alloc(64 * 8);
  float*    probs_ext = (float*)alloc(32 * 4);

  k_part<<<FRAG + 1, 256, 0, stream>>>(ei, ei + NE, cnt_blk, part,
                                       attn, czw, czb, chw, chb,
                                       lzw, lzb, lhw, lhb,
                                       Bz32, Bh32, cb2, probs_ext);
  k_csr<<<NBUCK, 1024, 0, stream>>>(cnt_blk, part, deg, csr, x, xs);
  k_main<<<NN / 8, 256, 0, stream>>>(xs, csr, deg, Bz32, Bh32, cb2, probs_ext,
                                     outw, outb, out);
}

// Round 13
// 306.457 us; speedup vs baseline: 1.1371x; 1.1371x over previous
//
#include <hip/hip_runtime.h>
#include <math.h>

#define NN 100000
#define NE 1600000
#define PERIODS 12
#define SLOTS 48     /* fixed Poisson(16) graph: max degree well below 48 (verified passing) */
#define NBUCK 98     /* ceil(NN/1024) node buckets */
#define FRAG 256     /* pass-1 partition blocks */
#define CAPB 128     /* per (bucket,block) cell capacity: mean 63.8, +8 sigma */

typedef unsigned short ushort_t;
typedef __attribute__((ext_vector_type(8))) short short8;
typedef __attribute__((ext_vector_type(16))) float floatx16;

union F4S8 { float4 f; short8 s; int4 i; };

__device__ __forceinline__ ushort_t f2bf(float f) {  // RNE fp32->bf16
  unsigned u = __float_as_uint(f);
  unsigned r = u + 0x7fffu + ((u >> 16) & 1u);
  return (ushort_t)(r >> 16);
}

__device__ __forceinline__ float bflo(unsigned u) { return __uint_as_float(u << 16); }
__device__ __forceinline__ float bfhi(unsigned u) { return __uint_as_float(u & 0xffff0000u); }

// A-tile offset for y element e (= f*12+p) of node slot 0: row p, col f;
// row stride 32 B (32 rows x 16 cols bf16). Node slot 1: +384 bytes.
__device__ __forceinline__ unsigned aoff2(unsigned e) {
  unsigned f = (e * 43691u) >> 19;   // e/12 for e<192
  unsigned p = e - f * 12u;
  return p * 32u + f * 2u;
}

// ---------------- pass 1: radix partition (LDS atomics only) + fused prep ----
// R9 confirmed: eliminating device-scope per-edge atomics was the build win.
// Each (bucket,block) cell is written by exactly one block -> lines fill in
// one XCD's L2 before eviction (no cross-XCD write ping-pong).
__global__ __launch_bounds__(256) void k_part(
    const int* __restrict__ src, const int* __restrict__ dst,
    int* __restrict__ cnt_blk, int* __restrict__ part,
    const float* __restrict__ attn,
    const float* __restrict__ czw, const float* __restrict__ czb,
    const float* __restrict__ chw, const float* __restrict__ chb,
    const float* __restrict__ lzw, const float* __restrict__ lzb,
    const float* __restrict__ lhw, const float* __restrict__ lhb,
    ushort_t* __restrict__ Bz32, ushort_t* __restrict__ Bh32,
    float2* __restrict__ cb2, float* __restrict__ probs_ext) {
  if (blockIdx.x == FRAG) {
    // ---- prep: fused weights in 32x32x16 B-frag order + softmax(attn) ----
    // H0 stays zero all periods => R path dead; only top 64 rows of lin_*.
    for (int t5 = threadIdx.x; t5 < 1024; t5 += 256) {
      int f = t5 >> 6, c = t5 & 63;
      float az = 0.f, ah = 0.f;
#pragma unroll 8
      for (int k = 0; k < 64; ++k) {
        az += czw[f * 64 + k] * lzw[k * 64 + c];
        ah += chw[f * 64 + k] * lhw[k * 64 + c];
      }
      int idx = (((c >> 5) * 64) + ((f >> 3) * 32) + (c & 31)) * 8 + (f & 7);
      Bz32[idx] = f2bf(az);
      Bh32[idx] = f2bf(ah);
    }
    if (threadIdx.x < 64) {
      int t = threadIdx.x;
      float vz = lzb[t], vh = lhb[t];
      for (int k = 0; k < 64; ++k) {
        vz += czb[k] * lzw[k * 64 + t];
        vh += chb[k] * lhw[k * 64 + t];
      }
      cb2[t] = make_float2(vz, vh);
    }
    if (threadIdx.x == 0) {
      float m = -1e30f;
      for (int p = 0; p < PERIODS; ++p) m = fmaxf(m, attn[p]);
      float e[PERIODS], s = 0.f;
      for (int p = 0; p < PERIODS; ++p) { e[p] = __expf(attn[p] - m); s += e[p]; }
      float inv = 1.f / s;
      for (int r = 0; r < 32; ++r)
        probs_ext[r] = (r < 12) ? e[r] * inv : ((r < 24) ? e[r - 12] * inv : 0.f);
    }
    return;
  }
  __shared__ int cnt[NBUCK];
  int tid = threadIdx.x, blk = blockIdx.x;
  for (int c = tid; c < NBUCK; c += 256) cnt[c] = 0;
  __syncthreads();
  for (unsigned i = blk * 256u + tid; i < NE / 4; i += FRAG * 256u) {
    int4 dv = ((const int4*)dst)[i];
    int4 sv = ((const int4*)src)[i];
    int d[4] = {dv.x, dv.y, dv.z, dv.w};
    int s[4] = {sv.x, sv.y, sv.z, sv.w};
#pragma unroll
    for (int k = 0; k < 4; ++k) {
      int cls = d[k] >> 10;
      int slot = atomicAdd(&cnt[cls], 1);
      if (slot < CAPB)
        part[(size_t)(cls * FRAG + blk) * CAPB + slot] = (d[k] & 1023) | (s[k] << 10);
    }
  }
  __syncthreads();
  for (int c = tid; c < NBUCK; c += 256) cnt_blk[blk * NBUCK + c] = cnt[c];
}

// ---------------- pass 2: per-bucket CSR build (16 frag-columns x 64 thr) ----
// Un-fused again: R12 showed folding streaming prescale into this 98-block
// grid serializes it at 98/256 CU utilization (-42us). Keep k_csr minimal.
__global__ __launch_bounds__(1024) void k_csr(const int* __restrict__ cnt_blk,
                                              const int* __restrict__ part,
                                              int* __restrict__ deg,
                                              int* __restrict__ csr) {
  __shared__ int fcnt[FRAG];
  __shared__ int cnt[1024];
  int b = blockIdx.x, tid = threadIdx.x;
  if (tid < FRAG) {
    int c = cnt_blk[tid * NBUCK + b];
    fcnt[tid] = c < CAPB ? c : CAPB;
  }
  cnt[tid] = 0;
  __syncthreads();
  int g = tid >> 6, it = tid & 63;   // 16 concurrent fragment columns
  for (int f = g; f < FRAG; f += 16) {
    int c = fcnt[f];
    const int* frag = part + (size_t)(b * FRAG + f) * CAPB;
    for (int i2 = it; i2 < c; i2 += 64) {
      int r = frag[i2];
      int dl = r & 1023;
      int slot = atomicAdd(&cnt[dl], 1);
      if (slot < SLOTS) csr[((size_t)(b * 1024 + dl)) * SLOTS + slot] = r >> 10;
    }
  }
  __syncthreads();
  int node = b * 1024 + tid;
  if (node < NN) deg[node] = cnt[tid];
}

// ---------------- prescale: xs[n] = dinv[n] * x[n], bf16 (full grid) --------
__global__ __launch_bounds__(256) void k_prescale(const float* __restrict__ x,
                                                  const int* __restrict__ deg,
                                                  ushort_t* __restrict__ xs) {
  int wid = threadIdx.x >> 6, l = threadIdx.x & 63;
  int n = blockIdx.x * 4 + wid;
  if (n >= NN) return;
  float dn = rsqrtf((float)(deg[n] + 1));
  const char* xb = (const char*)x;
  unsigned nb = (unsigned)n * 768u;
  float2 p = *(const float2*)(xb + nb + (unsigned)l * 8u);       // elems 2l, 2l+1
  float qv = *(const float*)(xb + nb + 512u + (unsigned)l * 4u); // elem 128+l
  char* ob = (char*)xs;
  unsigned ro = (unsigned)n * 384u;
  unsigned pk = (unsigned)f2bf(dn * p.x) | ((unsigned)f2bf(dn * p.y) << 16);
  *(unsigned*)(ob + ro + (unsigned)l * 4u) = pk;
  *(ushort_t*)(ob + ro + 256u + (unsigned)l * 2u) = f2bf(dn * qv);
}

// ---------------- fused gather + 32x32x16-MFMA collapsed-GRU + head ----------
// TWO nodes per wave; min-paired gather loop + tails (R10/R12 structure —
// measured best). 4 MFMAs per node pair; gates one rcp each; half-wave head.
__global__ __launch_bounds__(256) void k_main(
    const ushort_t* __restrict__ xs, const int* __restrict__ csr,
    const int* __restrict__ deg,
    const ushort_t* __restrict__ Bz32, const ushort_t* __restrict__ Bh32,
    const float2* __restrict__ cb2, const float* __restrict__ probs_ext,
    const float* __restrict__ out_w, const float* __restrict__ out_b,
    float* __restrict__ out) {
  __shared__ ushort_t Alds[4][32][16];   // per wave 1KB, row stride 32B
  int wid = __builtin_amdgcn_readfirstlane(threadIdx.x >> 6);
  int l = threadIdx.x & 63;
  int nA = blockIdx.x * 8 + wid * 2;     // grid = 12500 exact
  int nB = nA + 1;
  char* albase = (char*)&Alds[wid][0][0];
  if (l < 16) *(int4*)(albase + 768 + l * 16) = make_int4(0, 0, 0, 0);  // rows 24-31

  const char* xb = (const char*)xs;
  unsigned offA = (unsigned)l * 4u;          // bf16 pair: elems 2l, 2l+1
  unsigned offB = 256u + (unsigned)l * 2u;   // bf16: elem 128+l

  // self terms
  unsigned ba = (unsigned)nA * 384u, bb = (unsigned)nB * 384u;
  unsigned sua = *(const unsigned*)(xb + ba + offA);
  unsigned sqa = *(const ushort_t*)(xb + ba + offB);
  unsigned sub = *(const unsigned*)(xb + bb + offA);
  unsigned sqb = *(const ushort_t*)(xb + bb + offB);
  float aA0 = bflo(sua), aA1 = bfhi(sua), aA2 = bflo(sqa);
  float aB0 = bflo(sub), aB1 = bfhi(sub), aB2 = bflo(sqb);

  int2 dd = *(const int2*)(deg + nA);   // nA even -> 8B aligned
  int dA = dd.x, dB = dd.y;
  int cA = dA < SLOTS ? dA : SLOTS, cB = dB < SLOTS ? dB : SLOTS;
  const int* bktA = csr + (size_t)nA * SLOTS;   // wave-uniform -> s_loads
  const int* bktB = bktA + SLOTS;

  auto batchA = [&](int i) {
    int4 s4 = *(const int4*)(bktA + i);
    unsigned b0 = (unsigned)s4.x * 384u, b1 = (unsigned)s4.y * 384u;
    unsigned b2 = (unsigned)s4.z * 384u, b3 = (unsigned)s4.w * 384u;
    unsigned u0 = *(const unsigned*)(xb + b0 + offA), q0 = *(const ushort_t*)(xb + b0 + offB);
    unsigned u1 = *(const unsigned*)(xb + b1 + offA), q1 = *(const ushort_t*)(xb + b1 + offB);
    unsigned u2 = *(const unsigned*)(xb + b2 + offA), q2 = *(const ushort_t*)(xb + b2 + offB);
    unsigned u3 = *(const unsigned*)(xb + b3 + offA), q3 = *(const ushort_t*)(xb + b3 + offB);
    aA0 += bflo(u0); aA1 += bfhi(u0); aA2 += bflo(q0);
    aA0 += bflo(u1); aA1 += bfhi(u1); aA2 += bflo(q1);
    aA0 += bflo(u2); aA1 += bfhi(u2); aA2 += bflo(q2);
    aA0 += bflo(u3); aA1 += bfhi(u3); aA2 += bflo(q3);
  };
  auto batchB = [&](int i) {
    int4 s4 = *(const int4*)(bktB + i);
    unsigned b0 = (unsigned)s4.x * 384u, b1 = (unsigned)s4.y * 384u;
    unsigned b2 = (unsigned)s4.z * 384u, b3 = (unsigned)s4.w * 384u;
    unsigned u0 = *(const unsigned*)(xb + b0 + offA), q0 = *(const ushort_t*)(xb + b0 + offB);
    unsigned u1 = *(const unsigned*)(xb + b1 + offA), q1 = *(const ushort_t*)(xb + b1 + offB);
    unsigned u2 = *(const unsigned*)(xb + b2 + offA), q2 = *(const ushort_t*)(xb + b2 + offB);
    unsigned u3 = *(const unsigned*)(xb + b3 + offA), q3 = *(const ushort_t*)(xb + b3 + offB);
    aB0 += bflo(u0); aB1 += bfhi(u0); aB2 += bflo(q0);
    aB0 += bflo(u1); aB1 += bfhi(u1); aB2 += bflo(q1);
    aB0 += bflo(u2); aB1 += bfhi(u2); aB2 += bflo(q2);
    aB0 += bflo(u3); aB1 += bfhi(u3); aB2 += bflo(q3);
  };

  int cm = cA < cB ? cA : cB;
  int iA = 0, iB = 0;
  for (; iA + 4 <= cm; iA += 4, iB += 4) { batchA(iA); batchB(iB); }
  for (; iA + 4 <= cA; iA += 4) batchA(iA);
  for (; iB + 4 <= cB; iB += 4) batchB(iB);
  for (; iA < cA; ++iA) {
    int s = bktA[iA];
    unsigned b = (unsigned)s * 384u;
    unsigned u = *(const unsigned*)(xb + b + offA), q = *(const ushort_t*)(xb + b + offB);
    aA0 += bflo(u); aA1 += bfhi(u); aA2 += bflo(q);
  }
  for (; iB < cB; ++iB) {
    int s = bktB[iB];
    unsigned b = (unsigned)s * 384u;
    unsigned u = *(const unsigned*)(xb + b + offA), q = *(const ushort_t*)(xb + b + offB);
    aB0 += bflo(u); aB1 += bfhi(u); aB2 += bflo(q);
  }
  float dnA = rsqrtf((float)(dA + 1)), dnB = rsqrtf((float)(dB + 1));
  float yA0 = dnA * aA0, yA1 = dnA * aA1, yA2 = dnA * aA2;
  float yB0 = dnB * aB0, yB1 = dnB * aB1, yB2 = dnB * aB2;

  // ---- scatter both nodes' y into the 32x16 A-tile; single fence before read
  unsigned o0 = aoff2(2u * l), o1 = aoff2(2u * l + 1u), o2 = aoff2(128u + (unsigned)l);
  *(ushort_t*)(albase + o0) = f2bf(yA0);
  *(ushort_t*)(albase + o1) = f2bf(yA1);
  *(ushort_t*)(albase + o2) = f2bf(yA2);
  *(ushort_t*)(albase + 384u + o0) = f2bf(yB0);
  *(ushort_t*)(albase + 384u + o1) = f2bf(yB1);
  *(ushort_t*)(albase + 384u + o2) = f2bf(yB2);
  asm volatile("s_waitcnt lgkmcnt(0)" ::: "memory");
  F4S8 afr;
  afr.f = *(const float4*)(albase + (unsigned)(l & 31) * 32u + (unsigned)(l >> 5) * 16u);

  // ---- B fragments: 2 tiles x {z,h}, 16B/lane each (no pad lanes, K=16)
  F4S8 bz0, bz1, bh0, bh1;
  bz0.f = ((const float4*)Bz32)[l];
  bz1.f = ((const float4*)Bz32)[64 + l];
  bh0.f = ((const float4*)Bh32)[l];
  bh1.f = ((const float4*)Bh32)[64 + l];

  floatx16 zero16;
#pragma unroll
  for (int r = 0; r < 16; ++r) zero16[r] = 0.f;
  floatx16 az0 = __builtin_amdgcn_mfma_f32_32x32x16_bf16(afr.s, bz0.s, zero16, 0, 0, 0);
  floatx16 az1 = __builtin_amdgcn_mfma_f32_32x32x16_bf16(afr.s, bz1.s, zero16, 0, 0, 0);
  floatx16 ah0 = __builtin_amdgcn_mfma_f32_32x32x16_bf16(afr.s, bh0.s, zero16, 0, 0, 0);
  floatx16 ah1 = __builtin_amdgcn_mfma_f32_32x32x16_bf16(afr.s, bh1.s, zero16, 0, 0, 0);

  // ---- gates. C: col=lane&31(+32t), row=(reg&3)+8*(reg>>2)+4*(lane>>5).
  float2 cbv0 = cb2[l & 31], cbv1 = cb2[(l & 31) + 32];
  float prv[12];
  unsigned sby = (l & 32u) >> 1;   // (lane>>5)*16 bytes
#pragma unroll
  for (int r = 0; r < 12; ++r) {
    const int rb = (r & 3) + 8 * (r >> 2);
    prv[r] = *(const float*)((const char*)probs_ext + rb * 4 + sby);
  }
  bool sh = (l & 32) != 0;
  float hA[2], hB[2];
#pragma unroll
  for (int t = 0; t < 2; ++t) {
    float g0 = 0.f, g1 = 0.f, g2 = 0.f;
    float2 cbv = t ? cbv1 : cbv0;
#pragma unroll
    for (int r = 0; r < 12; ++r) {
      float zz = (t ? az1[r] : az0[r]) + cbv.x;
      float hh = (t ? ah1[r] : ah0[r]) + cbv.y;
      float ez = __expf(zz);
      float e2h = __expf(2.f * hh);
      float val = (e2h - 1.f) * __builtin_amdgcn_rcpf((1.f + ez) * (e2h + 1.f));
      float c = prv[r] * val;
      if ((r >> 2) == 0) g0 += c;
      else if ((r >> 2) == 1) g1 += c;
      else g2 += c;
    }
    float pa = g0 + (sh ? 0.f : g1);
    float pb = g2 + (sh ? g1 : 0.f);
    pa += __shfl_xor(pa, 32, 64);
    pb += __shfl_xor(pb, 32, 64);
    hA[t] = fmaxf(pa, 0.f);
    hB[t] = fmaxf(pb, 0.f);
  }

  // ---- head: half s=0 computes node A, s=1 node B; lane has feats {c0, c0+32}
  int c0 = l & 31;
  float4 w0 = ((const float4*)out_w)[c0];
  float4 w1 = ((const float4*)out_w)[c0 + 32];
  float h0 = sh ? hB[0] : hA[0];
  float h1 = sh ? hB[1] : hA[1];
  float l0 = h0 * w0.x; l0 = fmaf(h1, w1.x, l0);
  float l1 = h0 * w0.y; l1 = fmaf(h1, w1.y, l1);
  float l2 = h0 * w0.z; l2 = fmaf(h1, w1.z, l2);
  float l3 = h0 * w0.w; l3 = fmaf(h1, w1.w, l3);
#pragma unroll
  for (int o = 1; o < 32; o <<= 1) {   // stays within each 32-lane half
    l0 += __shfl_xor(l0, o, 64);
    l1 += __shfl_xor(l1, o, 64);
    l2 += __shfl_xor(l2, o, 64);
    l3 += __shfl_xor(l3, o, 64);
  }
  l0 += out_b[0]; l1 += out_b[1]; l2 += out_b[2]; l3 += out_b[3];
  float m = fmaxf(fmaxf(l0, l1), fmaxf(l2, l3));
  float e0 = __expf(l0 - m), e1 = __expf(l1 - m), e2 = __expf(l2 - m), e3 = __expf(l3 - m);
  float inv = __builtin_amdgcn_rcpf(e0 + e1 + e2 + e3);
  if (c0 < 4) {
    float v = (c0 == 0) ? e0 * inv : (c0 == 1) ? e1 * inv : (c0 == 2) ? e2 * inv : e3 * inv;
    out[(size_t)(sh ? nB : nA) * 4 + c0] = v;
  }
}

extern "C" void kernel_launch(void* const* d_in, const int* in_sizes, int n_in,
                              void* d_out, int out_size, void* d_ws, size_t ws_size,
                              hipStream_t stream) {
  const float* x    = (const float*)d_in[0];
  const int*   ei   = (const int*)d_in[1];   // (2, NE): src row then dst row
  const float* attn = (const float*)d_in[2];
  const float* czw  = (const float*)d_in[3];
  const float* czb  = (const float*)d_in[4];
  // d_in[5..6]: conv_r_* dead (H0*R == 0); d_in[11..12]: lin_r_* dead
  const float* chw  = (const float*)d_in[7];
  const float* chb  = (const float*)d_in[8];
  const float* lzw  = (const float*)d_in[9];
  const float* lzb  = (const float*)d_in[10];
  const float* lhw  = (const float*)d_in[13];
  const float* lhb  = (const float*)d_in[14];
  const float* outw = (const float*)d_in[15];
  const float* outb = (const float*)d_in[16];
  float* out = (float*)d_out;

  char* ws = (char*)d_ws;
  size_t off = 0;
  auto alloc = [&](size_t bytes) {
    void* p = ws + off;
    off += (bytes + 255) & ~(size_t)255;
    return p;
  };
  int*      deg       = (int*)alloc((size_t)NN * 4);                 // 0.4 MB
  int*      csr       = (int*)alloc((size_t)NN * SLOTS * 4);         // 19.2 MB
  // part (12.9 MB) overlaid with xs (38.4 MB): part fully consumed by k_csr
  // before k_prescale (separate kernel, stream-ordered) writes xs.
  void*     shared_region = alloc((size_t)NN * 192 * 2);
  int*      part      = (int*)shared_region;
  ushort_t* xs        = (ushort_t*)shared_region;
  int*      cnt_blk   = (int*)alloc((size_t)FRAG * NBUCK * 4);       // 100 KB
  ushort_t* Bz32      = (ushort_t*)alloc(2 * 64 * 8 * 2);
  ushort_t* Bh32      = (ushort_t*)alloc(2 * 64 * 8 * 2);
  float2*   cb2       = (float2*)alloc(64 * 8);
  float*    probs_ext = (float*)alloc(32 * 4);

  k_part<<<FRAG + 1, 256, 0, stream>>>(ei, ei + NE, cnt_blk, part,
                                       attn, czw, czb, chw, chb,
                                       lzw, lzb, lhw, lhb,
                                       Bz32, Bh32, cb2, probs_ext);
  k_csr<<<NBUCK, 1024, 0, stream>>>(cnt_blk, part, deg, csr);
  k_prescale<<<(NN + 3) / 4, 256, 0, stream>>>(x, deg, xs);
  k_main<<<NN / 8, 256, 0, stream>>>(xs, csr, deg, Bz32, Bh32, cb2, probs_ext,
                                     outw, outb, out);
}

// Round 14
// 304.164 us; speedup vs baseline: 1.1456x; 1.0075x over previous
//
#include <hip/hip_runtime.h>
#include <math.h>

#define NN 100000
#define NE 1600000
#define PERIODS 12
#define SLOTS 48     /* fixed Poisson(16) graph: max degree well below 48 (verified passing) */
#define NBUCK 391    /* ceil(NN/256) node buckets (256-node buckets for k_csr CU fill) */
#define FRAG 256     /* pass-1 partition blocks */
#define CAPB 48      /* per (bucket,block) cell capacity: Poisson(16), +8 sigma */

typedef unsigned short ushort_t;
typedef __attribute__((ext_vector_type(8))) short short8;
typedef __attribute__((ext_vector_type(16))) float floatx16;

union F4S8 { float4 f; short8 s; int4 i; };

__device__ __forceinline__ ushort_t f2bf(float f) {  // RNE fp32->bf16
  unsigned u = __float_as_uint(f);
  unsigned r = u + 0x7fffu + ((u >> 16) & 1u);
  return (ushort_t)(r >> 16);
}

__device__ __forceinline__ float bflo(unsigned u) { return __uint_as_float(u << 16); }
__device__ __forceinline__ float bfhi(unsigned u) { return __uint_as_float(u & 0xffff0000u); }

// A-tile offset for y element e (= f*12+p) of node slot 0: row p, col f;
// row stride 32 B (32 rows x 16 cols bf16). Node slot 1: +384 bytes.
__device__ __forceinline__ unsigned aoff2(unsigned e) {
  unsigned f = (e * 43691u) >> 19;   // e/12 for e<192
  unsigned p = e - f * 12u;
  return p * 32u + f * 2u;
}

// ---------------- pass 1: radix partition (LDS atomics only) + fused prep ----
// R9 confirmed: eliminating device-scope per-edge atomics was the build win.
// 256-node buckets (R14): record packs (dst&255)|(src<<8), 25 bits.
__global__ __launch_bounds__(256) void k_part(
    const int* __restrict__ src, const int* __restrict__ dst,
    int* __restrict__ cnt_blk, int* __restrict__ part,
    const float* __restrict__ attn,
    const float* __restrict__ czw, const float* __restrict__ czb,
    const float* __restrict__ chw, const float* __restrict__ chb,
    const float* __restrict__ lzw, const float* __restrict__ lzb,
    const float* __restrict__ lhw, const float* __restrict__ lhb,
    ushort_t* __restrict__ Bz32, ushort_t* __restrict__ Bh32,
    float2* __restrict__ cb2, float* __restrict__ probs_ext) {
  if (blockIdx.x == FRAG) {
    // ---- prep: fused weights in 32x32x16 B-frag order + softmax(attn) ----
    // H0 stays zero all periods => R path dead; only top 64 rows of lin_*.
    for (int t5 = threadIdx.x; t5 < 1024; t5 += 256) {
      int f = t5 >> 6, c = t5 & 63;
      float az = 0.f, ah = 0.f;
#pragma unroll 8
      for (int k = 0; k < 64; ++k) {
        az += czw[f * 64 + k] * lzw[k * 64 + c];
        ah += chw[f * 64 + k] * lhw[k * 64 + c];
      }
      int idx = (((c >> 5) * 64) + ((f >> 3) * 32) + (c & 31)) * 8 + (f & 7);
      Bz32[idx] = f2bf(az);
      Bh32[idx] = f2bf(ah);
    }
    if (threadIdx.x < 64) {
      int t = threadIdx.x;
      float vz = lzb[t], vh = lhb[t];
      for (int k = 0; k < 64; ++k) {
        vz += czb[k] * lzw[k * 64 + t];
        vh += chb[k] * lhw[k * 64 + t];
      }
      cb2[t] = make_float2(vz, vh);
    }
    if (threadIdx.x == 0) {
      float m = -1e30f;
      for (int p = 0; p < PERIODS; ++p) m = fmaxf(m, attn[p]);
      float e[PERIODS], s = 0.f;
      for (int p = 0; p < PERIODS; ++p) { e[p] = __expf(attn[p] - m); s += e[p]; }
      float inv = 1.f / s;
      for (int r = 0; r < 32; ++r)
        probs_ext[r] = (r < 12) ? e[r] * inv : ((r < 24) ? e[r - 12] * inv : 0.f);
    }
    return;
  }
  __shared__ int cnt[NBUCK];
  int tid = threadIdx.x, blk = blockIdx.x;
  for (int c = tid; c < NBUCK; c += 256) cnt[c] = 0;
  __syncthreads();
  for (unsigned i = blk * 256u + tid; i < NE / 4; i += FRAG * 256u) {
    int4 dv = ((const int4*)dst)[i];
    int4 sv = ((const int4*)src)[i];
    int d[4] = {dv.x, dv.y, dv.z, dv.w};
    int s[4] = {sv.x, sv.y, sv.z, sv.w};
#pragma unroll
    for (int k = 0; k < 4; ++k) {
      int cls = d[k] >> 8;
      int slot = atomicAdd(&cnt[cls], 1);
      if (slot < CAPB)
        part[(size_t)(cls * FRAG + blk) * CAPB + slot] = (d[k] & 255) | (s[k] << 8);
    }
  }
  __syncthreads();
  for (int c = tid; c < NBUCK; c += 256) cnt_blk[blk * NBUCK + c] = cnt[c];
}

// ---------------- pass 2: per-bucket CSR build (391 blocks -> full CU fill) --
// R13 post-mortem: 98-block k_csr used 38% of the machine. 256-node buckets
// give 391 blocks x 512 threads (2 threads per fragment-cell, ~8 entries
// each); LDS histogram; plain stores into this block's exclusive 48KB window.
__global__ __launch_bounds__(512) void k_csr(const int* __restrict__ cnt_blk,
                                             const int* __restrict__ part,
                                             int* __restrict__ deg,
                                             int* __restrict__ csr) {
  __shared__ int cnt[256];
  int b = blockIdx.x, tid = threadIdx.x;
  if (tid < 256) cnt[tid] = 0;
  __syncthreads();
  int f = tid & 255, sub = tid >> 8;   // 2 threads per cell
  int c = cnt_blk[f * NBUCK + b];
  c = c < CAPB ? c : CAPB;
  const int* cell = part + (size_t)(b * FRAG + f) * CAPB;
  for (int i = sub; i < c; i += 2) {
    int r = cell[i];
    int dl = r & 255;
    int slot = atomicAdd(&cnt[dl], 1);
    if (slot < SLOTS) csr[((size_t)(b * 256 + dl)) * SLOTS + slot] = r >> 8;
  }
  __syncthreads();
  int node = b * 256 + tid;
  if (tid < 256 && node < NN) deg[node] = cnt[tid];
}

// ---------------- prescale: xs[n] = dinv[n] * x[n], bf16 (full grid) --------
__global__ __launch_bounds__(256) void k_prescale(const float* __restrict__ x,
                                                  const int* __restrict__ deg,
                                                  ushort_t* __restrict__ xs) {
  int wid = threadIdx.x >> 6, l = threadIdx.x & 63;
  int n = blockIdx.x * 4 + wid;
  if (n >= NN) return;
  float dn = rsqrtf((float)(deg[n] + 1));
  const char* xb = (const char*)x;
  unsigned nb = (unsigned)n * 768u;
  float2 p = *(const float2*)(xb + nb + (unsigned)l * 8u);       // elems 2l, 2l+1
  float qv = *(const float*)(xb + nb + 512u + (unsigned)l * 4u); // elem 128+l
  char* ob = (char*)xs;
  unsigned ro = (unsigned)n * 384u;
  unsigned pk = (unsigned)f2bf(dn * p.x) | ((unsigned)f2bf(dn * p.y) << 16);
  *(unsigned*)(ob + ro + (unsigned)l * 4u) = pk;
  *(ushort_t*)(ob + ro + 256u + (unsigned)l * 2u) = f2bf(dn * qv);
}

// ---------------- fused gather + 32x32x16-MFMA collapsed-GRU + head ----------
// TWO nodes per wave; min-paired gather loop + tails (R10/R12 structure —
// measured best). 4 MFMAs per node pair; gates one rcp each; half-wave head.
// BIT-IDENTICAL to R13 (108.5us) for clean attribution of the build change.
__global__ __launch_bounds__(256) void k_main(
    const ushort_t* __restrict__ xs, const int* __restrict__ csr,
    const int* __restrict__ deg,
    const ushort_t* __restrict__ Bz32, const ushort_t* __restrict__ Bh32,
    const float2* __restrict__ cb2, const float* __restrict__ probs_ext,
    const float* __restrict__ out_w, const float* __restrict__ out_b,
    float* __restrict__ out) {
  __shared__ ushort_t Alds[4][32][16];   // per wave 1KB, row stride 32B
  int wid = __builtin_amdgcn_readfirstlane(threadIdx.x >> 6);
  int l = threadIdx.x & 63;
  int nA = blockIdx.x * 8 + wid * 2;     // grid = 12500 exact
  int nB = nA + 1;
  char* albase = (char*)&Alds[wid][0][0];
  if (l < 16) *(int4*)(albase + 768 + l * 16) = make_int4(0, 0, 0, 0);  // rows 24-31

  const char* xb = (const char*)xs;
  unsigned offA = (unsigned)l * 4u;          // bf16 pair: elems 2l, 2l+1
  unsigned offB = 256u + (unsigned)l * 2u;   // bf16: elem 128+l

  // self terms
  unsigned ba = (unsigned)nA * 384u, bb = (unsigned)nB * 384u;
  unsigned sua = *(const unsigned*)(xb + ba + offA);
  unsigned sqa = *(const ushort_t*)(xb + ba + offB);
  unsigned sub = *(const unsigned*)(xb + bb + offA);
  unsigned sqb = *(const ushort_t*)(xb + bb + offB);
  float aA0 = bflo(sua), aA1 = bfhi(sua), aA2 = bflo(sqa);
  float aB0 = bflo(sub), aB1 = bfhi(sub), aB2 = bflo(sqb);

  int2 dd = *(const int2*)(deg + nA);   // nA even -> 8B aligned
  int dA = dd.x, dB = dd.y;
  int cA = dA < SLOTS ? dA : SLOTS, cB = dB < SLOTS ? dB : SLOTS;
  const int* bktA = csr + (size_t)nA * SLOTS;   // wave-uniform -> s_loads
  const int* bktB = bktA + SLOTS;

  auto batchA = [&](int i) {
    int4 s4 = *(const int4*)(bktA + i);
    unsigned b0 = (unsigned)s4.x * 384u, b1 = (unsigned)s4.y * 384u;
    unsigned b2 = (unsigned)s4.z * 384u, b3 = (unsigned)s4.w * 384u;
    unsigned u0 = *(const unsigned*)(xb + b0 + offA), q0 = *(const ushort_t*)(xb + b0 + offB);
    unsigned u1 = *(const unsigned*)(xb + b1 + offA), q1 = *(const ushort_t*)(xb + b1 + offB);
    unsigned u2 = *(const unsigned*)(xb + b2 + offA), q2 = *(const ushort_t*)(xb + b2 + offB);
    unsigned u3 = *(const unsigned*)(xb + b3 + offA), q3 = *(const ushort_t*)(xb + b3 + offB);
    aA0 += bflo(u0); aA1 += bfhi(u0); aA2 += bflo(q0);
    aA0 += bflo(u1); aA1 += bfhi(u1); aA2 += bflo(q1);
    aA0 += bflo(u2); aA1 += bfhi(u2); aA2 += bflo(q2);
    aA0 += bflo(u3); aA1 += bfhi(u3); aA2 += bflo(q3);
  };
  auto batchB = [&](int i) {
    int4 s4 = *(const int4*)(bktB + i);
    unsigned b0 = (unsigned)s4.x * 384u, b1 = (unsigned)s4.y * 384u;
    unsigned b2 = (unsigned)s4.z * 384u, b3 = (unsigned)s4.w * 384u;
    unsigned u0 = *(const unsigned*)(xb + b0 + offA), q0 = *(const ushort_t*)(xb + b0 + offB);
    unsigned u1 = *(const unsigned*)(xb + b1 + offA), q1 = *(const ushort_t*)(xb + b1 + offB);
    unsigned u2 = *(const unsigned*)(xb + b2 + offA), q2 = *(const ushort_t*)(xb + b2 + offB);
    unsigned u3 = *(const unsigned*)(xb + b3 + offA), q3 = *(const ushort_t*)(xb + b3 + offB);
    aB0 += bflo(u0); aB1 += bfhi(u0); aB2 += bflo(q0);
    aB0 += bflo(u1); aB1 += bfhi(u1); aB2 += bflo(q1);
    aB0 += bflo(u2); aB1 += bfhi(u2); aB2 += bflo(q2);
    aB0 += bflo(u3); aB1 += bfhi(u3); aB2 += bflo(q3);
  };

  int cm = cA < cB ? cA : cB;
  int iA = 0, iB = 0;
  for (; iA + 4 <= cm; iA += 4, iB += 4) { batchA(iA); batchB(iB); }
  for (; iA + 4 <= cA; iA += 4) batchA(iA);
  for (; iB + 4 <= cB; iB += 4) batchB(iB);
  for (; iA < cA; ++iA) {
    int s = bktA[iA];
    unsigned b = (unsigned)s * 384u;
    unsigned u = *(const unsigned*)(xb + b + offA), q = *(const ushort_t*)(xb + b + offB);
    aA0 += bflo(u); aA1 += bfhi(u); aA2 += bflo(q);
  }
  for (; iB < cB; ++iB) {
    int s = bktB[iB];
    unsigned b = (unsigned)s * 384u;
    unsigned u = *(const unsigned*)(xb + b + offA), q = *(const ushort_t*)(xb + b + offB);
    aB0 += bflo(u); aB1 += bfhi(u); aB2 += bflo(q);
  }
  float dnA = rsqrtf((float)(dA + 1)), dnB = rsqrtf((float)(dB + 1));
  float yA0 = dnA * aA0, yA1 = dnA * aA1, yA2 = dnA * aA2;
  float yB0 = dnB * aB0, yB1 = dnB * aB1, yB2 = dnB * aB2;

  // ---- scatter both nodes' y into the 32x16 A-tile; single fence before read
  unsigned o0 = aoff2(2u * l), o1 = aoff2(2u * l + 1u), o2 = aoff2(128u + (unsigned)l);
  *(ushort_t*)(albase + o0) = f2bf(yA0);
  *(ushort_t*)(albase + o1) = f2bf(yA1);
  *(ushort_t*)(albase + o2) = f2bf(yA2);
  *(ushort_t*)(albase + 384u + o0) = f2bf(yB0);
  *(ushort_t*)(albase + 384u + o1) = f2bf(yB1);
  *(ushort_t*)(albase + 384u + o2) = f2bf(yB2);
  asm volatile("s_waitcnt lgkmcnt(0)" ::: "memory");
  F4S8 afr;
  afr.f = *(const float4*)(albase + (unsigned)(l & 31) * 32u + (unsigned)(l >> 5) * 16u);

  // ---- B fragments: 2 tiles x {z,h}, 16B/lane each (no pad lanes, K=16)
  F4S8 bz0, bz1, bh0, bh1;
  bz0.f = ((const float4*)Bz32)[l];
  bz1.f = ((const float4*)Bz32)[64 + l];
  bh0.f = ((const float4*)Bh32)[l];
  bh1.f = ((const float4*)Bh32)[64 + l];

  floatx16 zero16;
#pragma unroll
  for (int r = 0; r < 16; ++r) zero16[r] = 0.f;
  floatx16 az0 = __builtin_amdgcn_mfma_f32_32x32x16_bf16(afr.s, bz0.s, zero16, 0, 0, 0);
  floatx16 az1 = __builtin_amdgcn_mfma_f32_32x32x16_bf16(afr.s, bz1.s, zero16, 0, 0, 0);
  floatx16 ah0 = __builtin_amdgcn_mfma_f32_32x32x16_bf16(afr.s, bh0.s, zero16, 0, 0, 0);
  floatx16 ah1 = __builtin_amdgcn_mfma_f32_32x32x16_bf16(afr.s, bh1.s, zero16, 0, 0, 0);

  // ---- gates. C: col=lane&31(+32t), row=(reg&3)+8*(reg>>2)+4*(lane>>5).
  float2 cbv0 = cb2[l & 31], cbv1 = cb2[(l & 31) + 32];
  float prv[12];
  unsigned sby = (l & 32u) >> 1;   // (lane>>5)*16 bytes
#pragma unroll
  for (int r = 0; r < 12; ++r) {
    const int rb = (r & 3) + 8 * (r >> 2);
    prv[r] = *(const float*)((const char*)probs_ext + rb * 4 + sby);
  }
  bool sh = (l & 32) != 0;
  float hA[2], hB[2];
#pragma unroll
  for (int t = 0; t < 2; ++t) {
    float g0 = 0.f, g1 = 0.f, g2 = 0.f;
    float2 cbv = t ? cbv1 : cbv0;
#pragma unroll
    for (int r = 0; r < 12; ++r) {
      float zz = (t ? az1[r] : az0[r]) + cbv.x;
      float hh = (t ? ah1[r] : ah0[r]) + cbv.y;
      float ez = __expf(zz);
      float e2h = __expf(2.f * hh);
      float val = (e2h - 1.f) * __builtin_amdgcn_rcpf((1.f + ez) * (e2h + 1.f));
      float c = prv[r] * val;
      if ((r >> 2) == 0) g0 += c;
      else if ((r >> 2) == 1) g1 += c;
      else g2 += c;
    }
    float pa = g0 + (sh ? 0.f : g1);
    float pb = g2 + (sh ? g1 : 0.f);
    pa += __shfl_xor(pa, 32, 64);
    pb += __shfl_xor(pb, 32, 64);
    hA[t] = fmaxf(pa, 0.f);
    hB[t] = fmaxf(pb, 0.f);
  }

  // ---- head: half s=0 computes node A, s=1 node B; lane has feats {c0, c0+32}
  int c0 = l & 31;
  float4 w0 = ((const float4*)out_w)[c0];
  float4 w1 = ((const float4*)out_w)[c0 + 32];
  float h0 = sh ? hB[0] : hA[0];
  float h1 = sh ? hB[1] : hA[1];
  float l0 = h0 * w0.x; l0 = fmaf(h1, w1.x, l0);
  float l1 = h0 * w0.y; l1 = fmaf(h1, w1.y, l1);
  float l2 = h0 * w0.z; l2 = fmaf(h1, w1.z, l2);
  float l3 = h0 * w0.w; l3 = fmaf(h1, w1.w, l3);
#pragma unroll
  for (int o = 1; o < 32; o <<= 1) {   // stays within each 32-lane half
    l0 += __shfl_xor(l0, o, 64);
    l1 += __shfl_xor(l1, o, 64);
    l2 += __shfl_xor(l2, o, 64);
    l3 += __shfl_xor(l3, o, 64);
  }
  l0 += out_b[0]; l1 += out_b[1]; l2 += out_b[2]; l3 += out_b[3];
  float m = fmaxf(fmaxf(l0, l1), fmaxf(l2, l3));
  float e0 = __expf(l0 - m), e1 = __expf(l1 - m), e2 = __expf(l2 - m), e3 = __expf(l3 - m);
  float inv = __builtin_amdgcn_rcpf(e0 + e1 + e2 + e3);
  if (c0 < 4) {
    float v = (c0 == 0) ? e0 * inv : (c0 == 1) ? e1 * inv : (c0 == 2) ? e2 * inv : e3 * inv;
    out[(size_t)(sh ? nB : nA) * 4 + c0] = v;
  }
}

extern "C" void kernel_launch(void* const* d_in, const int* in_sizes, int n_in,
                              void* d_out, int out_size, void* d_ws, size_t ws_size,
                              hipStream_t stream) {
  const float* x    = (const float*)d_in[0];
  const int*   ei   = (const int*)d_in[1];   // (2, NE): src row then dst row
  const float* attn = (const float*)d_in[2];
  const float* czw  = (const float*)d_in[3];
  const float* czb  = (const float*)d_in[4];
  // d_in[5..6]: conv_r_* dead (H0*R == 0); d_in[11..12]: lin_r_* dead
  const float* chw  = (const float*)d_in[7];
  const float* chb  = (const float*)d_in[8];
  const float* lzw  = (const float*)d_in[9];
  const float* lzb  = (const float*)d_in[10];
  const float* lhw  = (const float*)d_in[13];
  const float* lhb  = (const float*)d_in[14];
  const float* outw = (const float*)d_in[15];
  const float* outb = (const float*)d_in[16];
  float* out = (float*)d_out;

  char* ws = (char*)d_ws;
  size_t off = 0;
  auto alloc = [&](size_t bytes) {
    void* p = ws + off;
    off += (bytes + 255) & ~(size_t)255;
    return p;
  };
  int*      deg       = (int*)alloc((size_t)NN * 4);                 // 0.4 MB
  int*      csr       = (int*)alloc((size_t)NN * SLOTS * 4);         // 19.2 MB
  // part (19.2 MB) overlaid with xs (38.4 MB): part fully consumed by k_csr
  // before k_prescale (separate kernel, stream-ordered) writes xs.
  void*     shared_region = alloc((size_t)NN * 192 * 2);
  int*      part      = (int*)shared_region;
  ushort_t* xs        = (ushort_t*)shared_region;
  int*      cnt_blk   = (int*)alloc((size_t)FRAG * NBUCK * 4);       // 400 KB
  ushort_t* Bz32      = (ushort_t*)alloc(2 * 64 * 8 * 2);
  ushort_t* Bh32      = (ushort_t*)alloc(2 * 64 * 8 * 2);
  float2*   cb2       = (float2*)alloc(64 * 8);
  float*    probs_ext = (float*)alloc(32 * 4);

  k_part<<<FRAG + 1, 256, 0, stream>>>(ei, ei + NE, cnt_blk, part,
                                       attn, czw, czb, chw, chb,
                                       lzw, lzb, lhw, lhb,
                                       Bz32, Bh32, cb2, probs_ext);
  k_csr<<<NBUCK, 512, 0, stream>>>(cnt_blk, part, deg, csr);
  k_prescale<<<(NN + 3) / 4, 256, 0, stream>>>(x, deg, xs);
  k_main<<<NN / 8, 256, 0, stream>>>(xs, csr, deg, Bz32, Bh32, cb2, probs_ext,
                                     outw, outb, out);
}